// Round 7
// baseline (240.216 us; speedup 1.0000x reference)
//
#include <hip/hip_runtime.h>
#include <hip/hip_bf16.h>

#define NB   16          // batch
#define NHW  16384       // H*W
#define CHW  1048576     // C*H*W
#define KC   576         // K*C (GEMM K)
#define KN   64          // output channels

typedef __attribute__((ext_vector_type(8))) short bf16x8;
typedef __attribute__((ext_vector_type(4))) float f32x4;
typedef __attribute__((ext_vector_type(2))) int i32x2;
typedef __attribute__((ext_vector_type(4))) int i32x4;

static __device__ __forceinline__ unsigned short f32_to_bf16(float f) {
  unsigned int u = __float_as_uint(f);
  unsigned int r = (u + 0x7FFFu + ((u >> 16) & 1u)) >> 16;  // RNE
  return (unsigned short)r;
}

static __device__ __forceinline__ void gload16(const void* g, void* l) {
  __builtin_amdgcn_global_load_lds(
      (const __attribute__((address_space(1))) void*)g,
      (__attribute__((address_space(3))) void*)l, 16, 0, 0);
}

static __device__ __forceinline__ bf16x8 pack_bfr(i32x2 a, i32x2 b) {
  i32x4 v; v.x = a.x; v.y = a.y; v.z = b.x; v.w = b.y;
  return __builtin_bit_cast(bf16x8, v);
}

// ---------------------------------------------------------------------------
// Kernel 1: x [B][CHW] fp32 -> xT [CHW][16] bf16 (32B row = all batches)
// ---------------------------------------------------------------------------
__global__ __launch_bounds__(256) void transpose_x_bf16(
    const float* __restrict__ x, unsigned short* __restrict__ xT) {
  const int i = blockIdx.x * 256 + threadIdx.x;
  unsigned short u[16];
#pragma unroll
  for (int b = 0; b < NB; ++b) u[b] = f32_to_bf16(x[(size_t)b * CHW + i]);
  int4* dst = (int4*)(xT + (size_t)i * NB);
  dst[0] = ((int4*)u)[0];
  dst[1] = ((int4*)u)[1];
}

// ---------------------------------------------------------------------------
// Kernel 2: pack w [KN][KC] fp32 into MFMA A-fragment order, bf16:
// wP[((ks*4+m)*64 + lane)*8 + j] = w[m*16 + (lane&15)][ks*32 + (lane>>4)*8 + j]
// ---------------------------------------------------------------------------
__global__ __launch_bounds__(256) void prep_w(
    const float* __restrict__ w, unsigned short* __restrict__ wP) {
  const int t = blockIdx.x * 256 + threadIdx.x;
  const int j  = t & 7;
  const int l  = (t >> 3) & 63;
  const int m  = (t >> 9) & 3;
  const int ks = t >> 11;                        // 0..17
  const int n  = m * 16 + (l & 15);
  const int k  = ks * 32 + (l >> 4) * 8 + j;
  wP[t] = f32_to_bf16(w[(size_t)n * KC + k]);
}

// ---------------------------------------------------------------------------
// Main kernel. ONE wave per block (64 thr), 4 pixels, 8KB LDS (2x4KB dbuf).
// Grid 4096, XCD-chunk swizzled. 18 k-steps of 32.
// Per step, issue order (all vmcnt-relevant ops pinned):
//   1. afr weight loads (asm global_load_dwordx4, FIRST -> oldest in queue)
//   2. idx prefetch for st+2 (C loads, fenced below the afr issue)
//   3. DMA gather (global_load_lds) for st+1 into the other buffer
//   4. s_waitcnt vmcnt(8): completes exactly {DMA(st), afr(st)};
//      {idx(st+2), DMA(st+1)} remain in flight  -> pipeline never drains.
//   5. 8x ds_read_b64_tr_b16 + 16 MFMA.
// This fixes R6's hidden serialization: afr as compiler-scheduled loads were
// the NEWEST outstanding VMEM at their use, and in-order vmcnt completion
// forced draining the just-issued DMA prefetch every step.
// ---------------------------------------------------------------------------
__global__ __launch_bounds__(64, 3) void hashconv_mfma(
    const int* __restrict__ ht, const unsigned short* __restrict__ xT,
    const unsigned short* __restrict__ wP, float* __restrict__ out) {
  const int lane = threadIdx.x & 63;
  const int hi   = lane >> 4;
  const int b16i = lane & 15;
  // bijective XCD-chunk swizzle: consecutive work chunks stay on one XCD
  const int bid  = blockIdx.x;
  const int sb   = (bid & 7) * 512 + (bid >> 3);
  const int p0   = sb * 4;

  __shared__ char Ls[8192];

  // per-lane DMA source decode (proven layout): lane i of DMA j fetches half
  // (i&1) of xT row ht[px=j][k(i)], k(i)=((i>>3)&3)*8+(i>>5)*4+((i>>1)&3)
  const int kk   = ((lane >> 3) & 3) * 8 + (lane >> 5) * 4 + ((lane >> 1) & 3);
  const int chof = (lane & 1) * 16;

  const unsigned ldsbase = (unsigned)(size_t)&Ls[0];
  const unsigned trbase  = ldsbase + hi * 128 + b16i * 8;

  const int* htj = ht + (size_t)p0 * KC + kk;
  const char* xTb = (const char*)xT;
  const unsigned woff = (unsigned)(lane * 16);   // voffset into wP step-chunk

  f32x4 acc[4][4];  // [m][px] — statically indexed everywhere (AGPRs)
#pragma unroll
  for (int m = 0; m < 4; ++m)
#pragma unroll
    for (int px = 0; px < 4; ++px) acc[m][px] = (f32x4){0.f, 0.f, 0.f, 0.f};

  // ---- prologue: idx(0) -> DMA(0) into buf0; preload idx(1) ----
  int c0, c1, c2, c3;
  {
    const int i0 = htj[0 * KC], i1 = htj[1 * KC], i2 = htj[2 * KC], i3 = htj[3 * KC];
    char* db = Ls;
    gload16(xTb + (size_t)(unsigned)i0 * 32 + chof, db);
    gload16(xTb + (size_t)(unsigned)i1 * 32 + chof, db + 1024);
    gload16(xTb + (size_t)(unsigned)i2 * 32 + chof, db + 2048);
    gload16(xTb + (size_t)(unsigned)i3 * 32 + chof, db + 3072);
    c0 = htj[0 * KC + 32]; c1 = htj[1 * KC + 32];
    c2 = htj[2 * KC + 32]; c3 = htj[3 * KC + 32];
  }

#pragma unroll
  for (int st = 0; st < 18; ++st) {
    // 1. afr loads FIRST (oldest in vmcnt queue; completed by the vmcnt below)
    bf16x8 a0, a1, a2, a3;
    {
      const char* wPs = (const char*)wP + st * 4096;
      asm volatile("global_load_dwordx4 %0, %1, %2 offset:0"
                   : "=v"(a0) : "v"(woff), "s"(wPs));
      asm volatile("global_load_dwordx4 %0, %1, %2 offset:1024"
                   : "=v"(a1) : "v"(woff), "s"(wPs));
      asm volatile("global_load_dwordx4 %0, %1, %2 offset:2048"
                   : "=v"(a2) : "v"(woff), "s"(wPs));
      asm volatile("global_load_dwordx4 %0, %1, %2 offset:3072"
                   : "=v"(a3) : "v"(woff), "s"(wPs));
    }
    asm volatile("" ::: "memory");  // pin: idx loads cannot hoist above afr
    // 2. idx prefetch for st+2
    int n0 = 0, n1 = 0, n2 = 0, n3 = 0;
    if (st < 16) {
      n0 = htj[0 * KC + (st + 2) * 32];
      n1 = htj[1 * KC + (st + 2) * 32];
      n2 = htj[2 * KC + (st + 2) * 32];
      n3 = htj[3 * KC + (st + 2) * 32];
    }
    // 3. DMA gather for st+1 into the other buffer
    if (st < 17) {
      char* db = Ls + (((st + 1) & 1) << 12);
      gload16(xTb + (size_t)(unsigned)c0 * 32 + chof, db);
      gload16(xTb + (size_t)(unsigned)c1 * 32 + chof, db + 1024);
      gload16(xTb + (size_t)(unsigned)c2 * 32 + chof, db + 2048);
      gload16(xTb + (size_t)(unsigned)c3 * 32 + chof, db + 3072);
    }
    // 4. counted drain: completes {DMA(st), afr(st)}, keeps prefetch in flight
    if (st <= 15)      asm volatile("s_waitcnt vmcnt(8)" ::: "memory");
    else if (st == 16) asm volatile("s_waitcnt vmcnt(4)" ::: "memory");
    else               asm volatile("s_waitcnt vmcnt(0)" ::: "memory");
    // 5. tr-reads + MFMA
    const unsigned trb = trbase + ((st & 1) << 12);
    i32x2 t00, t01, t10, t11, t20, t21, t30, t31;
    asm volatile("ds_read_b64_tr_b16 %0, %1 offset:0"    : "=v"(t00) : "v"(trb) : "memory");
    asm volatile("ds_read_b64_tr_b16 %0, %1 offset:512"  : "=v"(t01) : "v"(trb) : "memory");
    asm volatile("ds_read_b64_tr_b16 %0, %1 offset:1024" : "=v"(t10) : "v"(trb) : "memory");
    asm volatile("ds_read_b64_tr_b16 %0, %1 offset:1536" : "=v"(t11) : "v"(trb) : "memory");
    asm volatile("ds_read_b64_tr_b16 %0, %1 offset:2048" : "=v"(t20) : "v"(trb) : "memory");
    asm volatile("ds_read_b64_tr_b16 %0, %1 offset:2560" : "=v"(t21) : "v"(trb) : "memory");
    asm volatile("ds_read_b64_tr_b16 %0, %1 offset:3072" : "=v"(t30) : "v"(trb) : "memory");
    asm volatile("ds_read_b64_tr_b16 %0, %1 offset:3584" : "=v"(t31) : "v"(trb) : "memory");
    asm volatile("s_waitcnt lgkmcnt(0)" ::: "memory");
    __builtin_amdgcn_sched_barrier(0);
    const bf16x8 bfr0 = pack_bfr(t00, t01);
    const bf16x8 bfr1 = pack_bfr(t10, t11);
    const bf16x8 bfr2 = pack_bfr(t20, t21);
    const bf16x8 bfr3 = pack_bfr(t30, t31);
    acc[0][0] = __builtin_amdgcn_mfma_f32_16x16x32_bf16(a0, bfr0, acc[0][0], 0, 0, 0);
    acc[0][1] = __builtin_amdgcn_mfma_f32_16x16x32_bf16(a0, bfr1, acc[0][1], 0, 0, 0);
    acc[0][2] = __builtin_amdgcn_mfma_f32_16x16x32_bf16(a0, bfr2, acc[0][2], 0, 0, 0);
    acc[0][3] = __builtin_amdgcn_mfma_f32_16x16x32_bf16(a0, bfr3, acc[0][3], 0, 0, 0);
    acc[1][0] = __builtin_amdgcn_mfma_f32_16x16x32_bf16(a1, bfr0, acc[1][0], 0, 0, 0);
    acc[1][1] = __builtin_amdgcn_mfma_f32_16x16x32_bf16(a1, bfr1, acc[1][1], 0, 0, 0);
    acc[1][2] = __builtin_amdgcn_mfma_f32_16x16x32_bf16(a1, bfr2, acc[1][2], 0, 0, 0);
    acc[1][3] = __builtin_amdgcn_mfma_f32_16x16x32_bf16(a1, bfr3, acc[1][3], 0, 0, 0);
    acc[2][0] = __builtin_amdgcn_mfma_f32_16x16x32_bf16(a2, bfr0, acc[2][0], 0, 0, 0);
    acc[2][1] = __builtin_amdgcn_mfma_f32_16x16x32_bf16(a2, bfr1, acc[2][1], 0, 0, 0);
    acc[2][2] = __builtin_amdgcn_mfma_f32_16x16x32_bf16(a2, bfr2, acc[2][2], 0, 0, 0);
    acc[2][3] = __builtin_amdgcn_mfma_f32_16x16x32_bf16(a2, bfr3, acc[2][3], 0, 0, 0);
    acc[3][0] = __builtin_amdgcn_mfma_f32_16x16x32_bf16(a3, bfr0, acc[3][0], 0, 0, 0);
    acc[3][1] = __builtin_amdgcn_mfma_f32_16x16x32_bf16(a3, bfr1, acc[3][1], 0, 0, 0);
    acc[3][2] = __builtin_amdgcn_mfma_f32_16x16x32_bf16(a3, bfr2, acc[3][2], 0, 0, 0);
    acc[3][3] = __builtin_amdgcn_mfma_f32_16x16x32_bf16(a3, bfr3, acc[3][3], 0, 0, 0);
    // rotate idx pipeline
    if (st < 16) { c0 = n0; c1 = n1; c2 = n2; c3 = n3; }
  }

  // ---- epilogue: direct in-register transpose stores (all static) ----
  // C/D: col(b16i)=batch b, row in m-tile = hi*4+j, pixels p0..p0+3 (float4).
  // XCD-chunk swizzle makes adjacent blocks' 16B chunks merge in the same L2.
#pragma unroll
  for (int m = 0; m < 4; ++m)
#pragma unroll
    for (int j = 0; j < 4; ++j) {
      const float4 v = make_float4(acc[m][0][j], acc[m][1][j],
                                   acc[m][2][j], acc[m][3][j]);
      *(float4*)(out +
                 ((size_t)(b16i * 64 + m * 16 + hi * 4 + j)) * NHW + p0) = v;
    }
}

// ---------------------------------------------------------------------------
// Fallback (workspace too small): direct gather, slow but correct.
// ---------------------------------------------------------------------------
__global__ __launch_bounds__(256) void hashconv_naive_kernel(
    const int* __restrict__ ht, const float* __restrict__ x,
    const float* __restrict__ w, float* __restrict__ out) {
  const int wave = (blockIdx.x * 256 + threadIdx.x) >> 6;
  const int lane = threadIdx.x & 63;
  const int b = wave >> 14;
  const int p = wave & (NHW - 1);
  float acc = 0.f;
  for (int q = 0; q < KC; ++q) {
    const int idx = __builtin_amdgcn_readlane(ht[(size_t)p * KC + q], 0);
    const float xv = x[(size_t)b * CHW + idx];
    acc = fmaf(w[(size_t)lane * KC + q], xv, acc);
  }
  out[((size_t)(b * 64 + lane)) * NHW + p] = acc;
}

extern "C" void kernel_launch(void* const* d_in, const int* in_sizes, int n_in,
                              void* d_out, int out_size, void* d_ws, size_t ws_size,
                              hipStream_t stream) {
  const float* x  = (const float*)d_in[0];
  const int*   ht = (const int*)d_in[1];
  const float* w  = (const float*)d_in[2];
  float* out = (float*)d_out;

  const size_t xT_elems = (size_t)CHW * NB;      // bf16
  const size_t wP_elems = (size_t)18 * 4 * 64 * 8;
  const size_t need = (xT_elems + wP_elems) * sizeof(unsigned short);

  if (ws_size >= need) {
    unsigned short* xT = (unsigned short*)d_ws;
    unsigned short* wP = xT + xT_elems;
    transpose_x_bf16<<<CHW / 256, 256, 0, stream>>>(x, xT);
    prep_w<<<(int)(wP_elems / 256), 256, 0, stream>>>(w, wP);
    hashconv_mfma<<<NHW / 4, 64, 0, stream>>>(ht, xT, wP, out);
  } else {
    hashconv_naive_kernel<<<(NB * NHW * 64) / 256, 256, 0, stream>>>(ht, x, w, out);
  }
}

// Round 9
// 215.471 us; speedup vs baseline: 1.1148x; 1.1148x over previous
//
#include <hip/hip_runtime.h>
#include <hip/hip_bf16.h>

#define NB   16          // batch
#define NHW  16384       // H*W
#define CHW  1048576     // C*H*W
#define KC   576         // K*C (GEMM K)
#define KN   64          // output channels

typedef __attribute__((ext_vector_type(8))) short bf16x8;
typedef __attribute__((ext_vector_type(4))) float f32x4;
typedef __attribute__((ext_vector_type(2))) int i32x2;
typedef __attribute__((ext_vector_type(4))) int i32x4;

static __device__ __forceinline__ unsigned short f32_to_bf16(float f) {
  unsigned int u = __float_as_uint(f);
  unsigned int r = (u + 0x7FFFu + ((u >> 16) & 1u)) >> 16;  // RNE
  return (unsigned short)r;
}

static __device__ __forceinline__ void gload16(const void* g, void* l) {
  __builtin_amdgcn_global_load_lds(
      (const __attribute__((address_space(1))) void*)g,
      (__attribute__((address_space(3))) void*)l, 16, 0, 0);
}

static __device__ __forceinline__ bf16x8 pack_bfr(i32x2 a, i32x2 b) {
  i32x4 v; v.x = a.x; v.y = a.y; v.z = b.x; v.w = b.y;
  return __builtin_bit_cast(bf16x8, v);
}

// ---------------------------------------------------------------------------
// Kernel 1: x [B][CHW] fp32 -> xT [CHW][16] bf16 (32B row = all batches)
// ---------------------------------------------------------------------------
__global__ __launch_bounds__(256) void transpose_x_bf16(
    const float* __restrict__ x, unsigned short* __restrict__ xT) {
  const int i = blockIdx.x * 256 + threadIdx.x;
  unsigned short u[16];
#pragma unroll
  for (int b = 0; b < NB; ++b) u[b] = f32_to_bf16(x[(size_t)b * CHW + i]);
  int4* dst = (int4*)(xT + (size_t)i * NB);
  dst[0] = ((int4*)u)[0];
  dst[1] = ((int4*)u)[1];
}

// ---------------------------------------------------------------------------
// Kernel 2: pack w [KN][KC] fp32 into MFMA A-fragment order, bf16.
// ---------------------------------------------------------------------------
__global__ __launch_bounds__(256) void prep_w(
    const float* __restrict__ w, unsigned short* __restrict__ wP) {
  const int t = blockIdx.x * 256 + threadIdx.x;
  const int j  = t & 7;
  const int l  = (t >> 3) & 63;
  const int m  = (t >> 9) & 3;
  const int ks = t >> 11;                        // 0..17
  const int n  = m * 16 + (l & 15);
  const int k  = ks * 32 + (l >> 4) * 8 + j;
  wP[t] = f32_to_bf16(w[(size_t)n * KC + k]);
}

// ---------------------------------------------------------------------------
// Main kernel. 4 waves/block, 16 px; wave-private LDS (3 x 4KB) -> no
// barriers. 18 k-steps of 32. ALL loop VMEM hand-issued (asm idx with
// compile-time offsets, asm afr, DMA builtin); compiler has NO tracked
// loads in the loop -> cannot insert vmcnt waits -> hand counts are exact.
// R8's crash was register-pressure spill (scratch ops pollute vmcnt ->
// under-wait -> wild DMA address); fixed by: idx loads via fixed base +
// offset: immediate (no per-iter address VGPRs), single-generation af[4].
// Per step s: [afr(s) asm] [DMA(s+2)] [idx(s+4) asm] [W(s)] [tr-reads+MFMA].
// W(s) completes {..., DMA(s), afr(s)}; {DMA(s+1), idx(s+3)} stay in flight.
// Wait counts (simulated): prologue 8; s<=13 -> 8; s=14,15 -> 4; s>=16 -> 0.
// ---------------------------------------------------------------------------
__global__ __launch_bounds__(256, 2) void hashconv_mfma(
    const int* __restrict__ ht, const unsigned short* __restrict__ xT,
    const unsigned short* __restrict__ wP, float* __restrict__ out) {
  const int tid  = threadIdx.x;
  const int lane = tid & 63;
  const int wv   = __builtin_amdgcn_readfirstlane(tid >> 6);
  const int hi   = lane >> 4;
  const int b16i = lane & 15;
  const int p0   = blockIdx.x * 16;

  __shared__ char Ls[49152];

  // per-lane DMA source decode (proven tr_b16-readable layout)
  const int kk   = ((lane >> 3) & 3) * 8 + (lane >> 5) * 4 + ((lane >> 1) & 3);
  const int chof = (lane & 1) * 16;

  const unsigned ldsbase = (unsigned)(size_t)&Ls[0];
  const unsigned trb_ = ldsbase + wv * 12288 + hi * 128 + b16i * 8;
  char* const dbase = Ls + wv * 12288;

  const int* htp0 = ht + (size_t)(p0 + 4 * wv) * KC + kk;
  const int* htp1 = htp0 + KC;
  const int* htp2 = htp0 + 2 * KC;
  const int* htp3 = htp0 + 3 * KC;
  const char* xTb = (const char*)xT;
  const unsigned woff = (unsigned)(lane * 16);

  f32x4 acc[4][4];  // [m][px] — statically indexed everywhere
#pragma unroll
  for (int m = 0; m < 4; ++m)
#pragma unroll
    for (int px = 0; px < 4; ++px) acc[m][px] = (f32x4){0.f, 0.f, 0.f, 0.f};

  bf16x8 af0, af1, af2, af3;  // single-generation weight fragments
  int X[2][4];                // idx pipeline, constant indices only

  // ---- prologue ----
  // idx(0), idx(1): plain C loads, fully consumed before any asm issues.
  const int q00 = htp0[0],  q01 = htp1[0],  q02 = htp2[0],  q03 = htp3[0];
  const int q10 = htp0[32], q11 = htp1[32], q12 = htp2[32], q13 = htp3[32];
  asm volatile("" ::: "memory");
  // asm idx(2) -> X[0] (offset 2*128), idx(3) -> X[1] (offset 3*128)
  asm volatile("global_load_dword %0, %1, off offset:256" : "=v"(X[0][0]) : "v"(htp0) : "memory");
  asm volatile("global_load_dword %0, %1, off offset:256" : "=v"(X[0][1]) : "v"(htp1) : "memory");
  asm volatile("global_load_dword %0, %1, off offset:256" : "=v"(X[0][2]) : "v"(htp2) : "memory");
  asm volatile("global_load_dword %0, %1, off offset:256" : "=v"(X[0][3]) : "v"(htp3) : "memory");
  asm volatile("global_load_dword %0, %1, off offset:384" : "=v"(X[1][0]) : "v"(htp0) : "memory");
  asm volatile("global_load_dword %0, %1, off offset:384" : "=v"(X[1][1]) : "v"(htp1) : "memory");
  asm volatile("global_load_dword %0, %1, off offset:384" : "=v"(X[1][2]) : "v"(htp2) : "memory");
  asm volatile("global_load_dword %0, %1, off offset:384" : "=v"(X[1][3]) : "v"(htp3) : "memory");
  asm volatile("" ::: "memory");
  // DMA(0) -> buf0, DMA(1) -> buf1
  gload16(xTb + (size_t)(unsigned)q00 * 32 + chof, dbase);
  gload16(xTb + (size_t)(unsigned)q01 * 32 + chof, dbase + 1024);
  gload16(xTb + (size_t)(unsigned)q02 * 32 + chof, dbase + 2048);
  gload16(xTb + (size_t)(unsigned)q03 * 32 + chof, dbase + 3072);
  asm volatile("" ::: "memory");
  gload16(xTb + (size_t)(unsigned)q10 * 32 + chof, dbase + 4096);
  gload16(xTb + (size_t)(unsigned)q11 * 32 + chof, dbase + 4096 + 1024);
  gload16(xTb + (size_t)(unsigned)q12 * 32 + chof, dbase + 4096 + 2048);
  gload16(xTb + (size_t)(unsigned)q13 * 32 + chof, dbase + 4096 + 3072);
  // prologue wait: completes idx(2),idx(3); DMA(0),DMA(1) stay in flight
  asm volatile("s_waitcnt vmcnt(8)" ::: "memory");

#pragma unroll 18
  for (int st = 0; st < 18; ++st) {
    // ---- issue afr(st) (asm; completed by W(st) below) ----
    {
      const char* wPs = (const char*)wP + (size_t)st * 4096;
      asm volatile("global_load_dwordx4 %0, %1, %2 offset:0"    : "=v"(af0) : "v"(woff), "s"(wPs));
      asm volatile("global_load_dwordx4 %0, %1, %2 offset:1024" : "=v"(af1) : "v"(woff), "s"(wPs));
      asm volatile("global_load_dwordx4 %0, %1, %2 offset:2048" : "=v"(af2) : "v"(woff), "s"(wPs));
      asm volatile("global_load_dwordx4 %0, %1, %2 offset:3072" : "=v"(af3) : "v"(woff), "s"(wPs));
    }
    asm volatile("" ::: "memory");
    // ---- issue DMA(st+2) into buf[(st+2)%3], consuming X[st&1] ----
    if (st < 16) {
      char* db = dbase + ((st + 2) % 3) * 4096;
      gload16(xTb + (size_t)(unsigned)X[st & 1][0] * 32 + chof, db);
      gload16(xTb + (size_t)(unsigned)X[st & 1][1] * 32 + chof, db + 1024);
      gload16(xTb + (size_t)(unsigned)X[st & 1][2] * 32 + chof, db + 2048);
      gload16(xTb + (size_t)(unsigned)X[st & 1][3] * 32 + chof, db + 3072);
    }
    asm volatile("" ::: "memory");
    // ---- issue idx(st+4) into X[st&1] (fixed base + imm offset) ----
    if (st < 14) {
      switch (st + 4) {
#define IDX_CASE(N)                                                                               \
        case N:                                                                                   \
          asm volatile("global_load_dword %0, %1, off offset:" #N "*128" : "=v"(X[st & 1][0]) : "v"(htp0) : "memory"); \
          asm volatile("global_load_dword %0, %1, off offset:" #N "*128" : "=v"(X[st & 1][1]) : "v"(htp1) : "memory"); \
          asm volatile("global_load_dword %0, %1, off offset:" #N "*128" : "=v"(X[st & 1][2]) : "v"(htp2) : "memory"); \
          asm volatile("global_load_dword %0, %1, off offset:" #N "*128" : "=v"(X[st & 1][3]) : "v"(htp3) : "memory"); \
          break;
        IDX_CASE(4) IDX_CASE(5) IDX_CASE(6) IDX_CASE(7) IDX_CASE(8) IDX_CASE(9)
        IDX_CASE(10) IDX_CASE(11) IDX_CASE(12) IDX_CASE(13) IDX_CASE(14)
        IDX_CASE(15) IDX_CASE(16) IDX_CASE(17)
#undef IDX_CASE
      }
    }
    // ---- W(st): completes {DMA(st), afr(st)}; keeps prefetch in flight ----
    if (st <= 13)      asm volatile("s_waitcnt vmcnt(8)" ::: "memory");
    else if (st <= 15) asm volatile("s_waitcnt vmcnt(4)" ::: "memory");
    else               asm volatile("s_waitcnt vmcnt(0)" ::: "memory");
    // ---- tr-reads of buf[st%3] + MFMA ----
    const unsigned trb = trb_ + (unsigned)((st % 3) * 4096);
    i32x2 t00, t01, t10, t11, t20, t21, t30, t31;
    asm volatile("ds_read_b64_tr_b16 %0, %1 offset:0"    : "=v"(t00) : "v"(trb) : "memory");
    asm volatile("ds_read_b64_tr_b16 %0, %1 offset:512"  : "=v"(t01) : "v"(trb) : "memory");
    asm volatile("ds_read_b64_tr_b16 %0, %1 offset:1024" : "=v"(t10) : "v"(trb) : "memory");
    asm volatile("ds_read_b64_tr_b16 %0, %1 offset:1536" : "=v"(t11) : "v"(trb) : "memory");
    asm volatile("ds_read_b64_tr_b16 %0, %1 offset:2048" : "=v"(t20) : "v"(trb) : "memory");
    asm volatile("ds_read_b64_tr_b16 %0, %1 offset:2560" : "=v"(t21) : "v"(trb) : "memory");
    asm volatile("ds_read_b64_tr_b16 %0, %1 offset:3072" : "=v"(t30) : "v"(trb) : "memory");
    asm volatile("ds_read_b64_tr_b16 %0, %1 offset:3584" : "=v"(t31) : "v"(trb) : "memory");
    asm volatile("s_waitcnt lgkmcnt(0)" ::: "memory");
    __builtin_amdgcn_sched_barrier(0);
    const bf16x8 bfr0 = pack_bfr(t00, t01);
    const bf16x8 bfr1 = pack_bfr(t10, t11);
    const bf16x8 bfr2 = pack_bfr(t20, t21);
    const bf16x8 bfr3 = pack_bfr(t30, t31);
    acc[0][0] = __builtin_amdgcn_mfma_f32_16x16x32_bf16(af0, bfr0, acc[0][0], 0, 0, 0);
    acc[0][1] = __builtin_amdgcn_mfma_f32_16x16x32_bf16(af0, bfr1, acc[0][1], 0, 0, 0);
    acc[0][2] = __builtin_amdgcn_mfma_f32_16x16x32_bf16(af0, bfr2, acc[0][2], 0, 0, 0);
    acc[0][3] = __builtin_amdgcn_mfma_f32_16x16x32_bf16(af0, bfr3, acc[0][3], 0, 0, 0);
    acc[1][0] = __builtin_amdgcn_mfma_f32_16x16x32_bf16(af1, bfr0, acc[1][0], 0, 0, 0);
    acc[1][1] = __builtin_amdgcn_mfma_f32_16x16x32_bf16(af1, bfr1, acc[1][1], 0, 0, 0);
    acc[1][2] = __builtin_amdgcn_mfma_f32_16x16x32_bf16(af1, bfr2, acc[1][2], 0, 0, 0);
    acc[1][3] = __builtin_amdgcn_mfma_f32_16x16x32_bf16(af1, bfr3, acc[1][3], 0, 0, 0);
    acc[2][0] = __builtin_amdgcn_mfma_f32_16x16x32_bf16(af2, bfr0, acc[2][0], 0, 0, 0);
    acc[2][1] = __builtin_amdgcn_mfma_f32_16x16x32_bf16(af2, bfr1, acc[2][1], 0, 0, 0);
    acc[2][2] = __builtin_amdgcn_mfma_f32_16x16x32_bf16(af2, bfr2, acc[2][2], 0, 0, 0);
    acc[2][3] = __builtin_amdgcn_mfma_f32_16x16x32_bf16(af2, bfr3, acc[2][3], 0, 0, 0);
    acc[3][0] = __builtin_amdgcn_mfma_f32_16x16x32_bf16(af3, bfr0, acc[3][0], 0, 0, 0);
    acc[3][1] = __builtin_amdgcn_mfma_f32_16x16x32_bf16(af3, bfr1, acc[3][1], 0, 0, 0);
    acc[3][2] = __builtin_amdgcn_mfma_f32_16x16x32_bf16(af3, bfr2, acc[3][2], 0, 0, 0);
    acc[3][3] = __builtin_amdgcn_mfma_f32_16x16x32_bf16(af3, bfr3, acc[3][3], 0, 0, 0);
  }

  // ---- epilogue: direct in-register transpose stores (all static) ----
  // C/D: col(b16i)=batch b, row in m-tile = hi*4+j, pixel = p0+4wv+px.
  // 4 waves of the block fill each 64B output line -> merges in L2.
#pragma unroll
  for (int m = 0; m < 4; ++m)
#pragma unroll
    for (int j = 0; j < 4; ++j) {
      const float4 v = make_float4(acc[m][0][j], acc[m][1][j],
                                   acc[m][2][j], acc[m][3][j]);
      *(float4*)(out +
                 ((size_t)(b16i * 64 + m * 16 + hi * 4 + j)) * NHW +
                 p0 + 4 * wv) = v;
    }
}

// ---------------------------------------------------------------------------
// Fallback (workspace too small): direct gather, slow but correct.
// ---------------------------------------------------------------------------
__global__ __launch_bounds__(256) void hashconv_naive_kernel(
    const int* __restrict__ ht, const float* __restrict__ x,
    const float* __restrict__ w, float* __restrict__ out) {
  const int wave = (blockIdx.x * 256 + threadIdx.x) >> 6;
  const int lane = threadIdx.x & 63;
  const int b = wave >> 14;
  const int p = wave & (NHW - 1);
  float acc = 0.f;
  for (int q = 0; q < KC; ++q) {
    const int idx = __builtin_amdgcn_readlane(ht[(size_t)p * KC + q], 0);
    const float xv = x[(size_t)b * CHW + idx];
    acc = fmaf(w[(size_t)lane * KC + q], xv, acc);
  }
  out[((size_t)(b * 64 + lane)) * NHW + p] = acc;
}

extern "C" void kernel_launch(void* const* d_in, const int* in_sizes, int n_in,
                              void* d_out, int out_size, void* d_ws, size_t ws_size,
                              hipStream_t stream) {
  const float* x  = (const float*)d_in[0];
  const int*   ht = (const int*)d_in[1];
  const float* w  = (const float*)d_in[2];
  float* out = (float*)d_out;

  const size_t xT_elems = (size_t)CHW * NB;      // bf16
  const size_t wP_elems = (size_t)18 * 4 * 64 * 8;
  const size_t need = (xT_elems + wP_elems) * sizeof(unsigned short);

  if (ws_size >= need) {
    unsigned short* xT = (unsigned short*)d_ws;
    unsigned short* wP = xT + xT_elems;
    transpose_x_bf16<<<CHW / 256, 256, 0, stream>>>(x, xT);
    prep_w<<<(int)(wP_elems / 256), 256, 0, stream>>>(w, wP);
    hashconv_mfma<<<NHW / 16, 256, 0, stream>>>(ht, xT, wP, out);
  } else {
    hashconv_naive_kernel<<<(NB * NHW * 64) / 256, 256, 0, stream>>>(ht, x, w, out);
  }
}

// Round 10
// 213.968 us; speedup vs baseline: 1.1227x; 1.0070x over previous
//
#include <hip/hip_runtime.h>
#include <hip/hip_bf16.h>

#define NB   16          // batch
#define NHW  16384       // H*W
#define CHW  1048576     // C*H*W
#define KC   576         // K*C (GEMM K)
#define KN   64          // output channels

typedef __attribute__((ext_vector_type(8))) short bf16x8;
typedef __attribute__((ext_vector_type(4))) float f32x4;
typedef __attribute__((ext_vector_type(2))) int i32x2;
typedef __attribute__((ext_vector_type(4))) int i32x4;

static __device__ __forceinline__ unsigned short f32_to_bf16(float f) {
  unsigned int u = __float_as_uint(f);
  unsigned int r = (u + 0x7FFFu + ((u >> 16) & 1u)) >> 16;  // RNE
  return (unsigned short)r;
}

static __device__ __forceinline__ void gload16(const void* g, void* l) {
  __builtin_amdgcn_global_load_lds(
      (const __attribute__((address_space(1))) void*)g,
      (__attribute__((address_space(3))) void*)l, 16, 0, 0);
}

static __device__ __forceinline__ bf16x8 pack_bfr(i32x2 a, i32x2 b) {
  i32x4 v; v.x = a.x; v.y = a.y; v.z = b.x; v.w = b.y;
  return __builtin_bit_cast(bf16x8, v);
}

// ---------------------------------------------------------------------------
// Kernel 1: x [B][CHW] fp32 -> xT [CHW][16] bf16 (32B row = all batches)
// ---------------------------------------------------------------------------
__global__ __launch_bounds__(256) void transpose_x_bf16(
    const float* __restrict__ x, unsigned short* __restrict__ xT) {
  const int i = blockIdx.x * 256 + threadIdx.x;
  unsigned short u[16];
#pragma unroll
  for (int b = 0; b < NB; ++b) u[b] = f32_to_bf16(x[(size_t)b * CHW + i]);
  int4* dst = (int4*)(xT + (size_t)i * NB);
  dst[0] = ((int4*)u)[0];
  dst[1] = ((int4*)u)[1];
}

// ---------------------------------------------------------------------------
// Kernel 2: pack w [KN][KC] fp32 into MFMA A-fragment order, bf16.
// ---------------------------------------------------------------------------
__global__ __launch_bounds__(256) void prep_w(
    const float* __restrict__ w, unsigned short* __restrict__ wP) {
  const int t = blockIdx.x * 256 + threadIdx.x;
  const int j  = t & 7;
  const int l  = (t >> 3) & 63;
  const int m  = (t >> 9) & 3;
  const int ks = t >> 11;                        // 0..17
  const int n  = m * 16 + (l & 15);
  const int k  = ks * 32 + (l >> 4) * 8 + j;
  wP[t] = f32_to_bf16(w[(size_t)n * KC + k]);
}

// ---------------------------------------------------------------------------
// Main kernel — identical schedule to R9 (proven correct: hand-issued VMEM,
// exact vmcnt counts, depth-2 DMA pipeline, wave-private LDS, no barriers).
// SINGLE change vs R9: launch_bounds(256,2) -> (256,3), i.e. 2 -> 3 blocks/CU
// (12 waves/CU). Little's-law test: if the ~2.7 TB/s effective gather
// bandwidth is source-side (outstanding-request count), +50% resident waves
// raises it; if it is a fabric-side random-64B-line ceiling, no change and
// the roofline is established.
// ---------------------------------------------------------------------------
__global__ __launch_bounds__(256, 3) void hashconv_mfma(
    const int* __restrict__ ht, const unsigned short* __restrict__ xT,
    const unsigned short* __restrict__ wP, float* __restrict__ out) {
  const int tid  = threadIdx.x;
  const int lane = tid & 63;
  const int wv   = __builtin_amdgcn_readfirstlane(tid >> 6);
  const int hi   = lane >> 4;
  const int b16i = lane & 15;
  const int p0   = blockIdx.x * 16;

  __shared__ char Ls[49152];

  // per-lane DMA source decode (proven tr_b16-readable layout)
  const int kk   = ((lane >> 3) & 3) * 8 + (lane >> 5) * 4 + ((lane >> 1) & 3);
  const int chof = (lane & 1) * 16;

  const unsigned ldsbase = (unsigned)(size_t)&Ls[0];
  const unsigned trb_ = ldsbase + wv * 12288 + hi * 128 + b16i * 8;
  char* const dbase = Ls + wv * 12288;

  const int* htp0 = ht + (size_t)(p0 + 4 * wv) * KC + kk;
  const int* htp1 = htp0 + KC;
  const int* htp2 = htp0 + 2 * KC;
  const int* htp3 = htp0 + 3 * KC;
  const char* xTb = (const char*)xT;
  const unsigned woff = (unsigned)(lane * 16);

  f32x4 acc[4][4];  // [m][px] — statically indexed everywhere
#pragma unroll
  for (int m = 0; m < 4; ++m)
#pragma unroll
    for (int px = 0; px < 4; ++px) acc[m][px] = (f32x4){0.f, 0.f, 0.f, 0.f};

  bf16x8 af0, af1, af2, af3;  // single-generation weight fragments
  int X[2][4];                // idx pipeline, constant indices only

  // ---- prologue ----
  // idx(0), idx(1): plain C loads, fully consumed before any asm issues.
  const int q00 = htp0[0],  q01 = htp1[0],  q02 = htp2[0],  q03 = htp3[0];
  const int q10 = htp0[32], q11 = htp1[32], q12 = htp2[32], q13 = htp3[32];
  asm volatile("" ::: "memory");
  // asm idx(2) -> X[0] (offset 2*128), idx(3) -> X[1] (offset 3*128)
  asm volatile("global_load_dword %0, %1, off offset:256" : "=v"(X[0][0]) : "v"(htp0) : "memory");
  asm volatile("global_load_dword %0, %1, off offset:256" : "=v"(X[0][1]) : "v"(htp1) : "memory");
  asm volatile("global_load_dword %0, %1, off offset:256" : "=v"(X[0][2]) : "v"(htp2) : "memory");
  asm volatile("global_load_dword %0, %1, off offset:256" : "=v"(X[0][3]) : "v"(htp3) : "memory");
  asm volatile("global_load_dword %0, %1, off offset:384" : "=v"(X[1][0]) : "v"(htp0) : "memory");
  asm volatile("global_load_dword %0, %1, off offset:384" : "=v"(X[1][1]) : "v"(htp1) : "memory");
  asm volatile("global_load_dword %0, %1, off offset:384" : "=v"(X[1][2]) : "v"(htp2) : "memory");
  asm volatile("global_load_dword %0, %1, off offset:384" : "=v"(X[1][3]) : "v"(htp3) : "memory");
  asm volatile("" ::: "memory");
  // DMA(0) -> buf0, DMA(1) -> buf1
  gload16(xTb + (size_t)(unsigned)q00 * 32 + chof, dbase);
  gload16(xTb + (size_t)(unsigned)q01 * 32 + chof, dbase + 1024);
  gload16(xTb + (size_t)(unsigned)q02 * 32 + chof, dbase + 2048);
  gload16(xTb + (size_t)(unsigned)q03 * 32 + chof, dbase + 3072);
  asm volatile("" ::: "memory");
  gload16(xTb + (size_t)(unsigned)q10 * 32 + chof, dbase + 4096);
  gload16(xTb + (size_t)(unsigned)q11 * 32 + chof, dbase + 4096 + 1024);
  gload16(xTb + (size_t)(unsigned)q12 * 32 + chof, dbase + 4096 + 2048);
  gload16(xTb + (size_t)(unsigned)q13 * 32 + chof, dbase + 4096 + 3072);
  // prologue wait: completes idx(2),idx(3); DMA(0),DMA(1) stay in flight
  asm volatile("s_waitcnt vmcnt(8)" ::: "memory");

#pragma unroll 18
  for (int st = 0; st < 18; ++st) {
    // ---- issue afr(st) (asm; completed by W(st) below) ----
    {
      const char* wPs = (const char*)wP + (size_t)st * 4096;
      asm volatile("global_load_dwordx4 %0, %1, %2 offset:0"    : "=v"(af0) : "v"(woff), "s"(wPs));
      asm volatile("global_load_dwordx4 %0, %1, %2 offset:1024" : "=v"(af1) : "v"(woff), "s"(wPs));
      asm volatile("global_load_dwordx4 %0, %1, %2 offset:2048" : "=v"(af2) : "v"(woff), "s"(wPs));
      asm volatile("global_load_dwordx4 %0, %1, %2 offset:3072" : "=v"(af3) : "v"(woff), "s"(wPs));
    }
    asm volatile("" ::: "memory");
    // ---- issue DMA(st+2) into buf[(st+2)%3], consuming X[st&1] ----
    if (st < 16) {
      char* db = dbase + ((st + 2) % 3) * 4096;
      gload16(xTb + (size_t)(unsigned)X[st & 1][0] * 32 + chof, db);
      gload16(xTb + (size_t)(unsigned)X[st & 1][1] * 32 + chof, db + 1024);
      gload16(xTb + (size_t)(unsigned)X[st & 1][2] * 32 + chof, db + 2048);
      gload16(xTb + (size_t)(unsigned)X[st & 1][3] * 32 + chof, db + 3072);
    }
    asm volatile("" ::: "memory");
    // ---- issue idx(st+4) into X[st&1] (fixed base + imm offset) ----
    if (st < 14) {
      switch (st + 4) {
#define IDX_CASE(N)                                                                               \
        case N:                                                                                   \
          asm volatile("global_load_dword %0, %1, off offset:" #N "*128" : "=v"(X[st & 1][0]) : "v"(htp0) : "memory"); \
          asm volatile("global_load_dword %0, %1, off offset:" #N "*128" : "=v"(X[st & 1][1]) : "v"(htp1) : "memory"); \
          asm volatile("global_load_dword %0, %1, off offset:" #N "*128" : "=v"(X[st & 1][2]) : "v"(htp2) : "memory"); \
          asm volatile("global_load_dword %0, %1, off offset:" #N "*128" : "=v"(X[st & 1][3]) : "v"(htp3) : "memory"); \
          break;
        IDX_CASE(4) IDX_CASE(5) IDX_CASE(6) IDX_CASE(7) IDX_CASE(8) IDX_CASE(9)
        IDX_CASE(10) IDX_CASE(11) IDX_CASE(12) IDX_CASE(13) IDX_CASE(14)
        IDX_CASE(15) IDX_CASE(16) IDX_CASE(17)
#undef IDX_CASE
      }
    }
    // ---- W(st): completes {DMA(st), afr(st)}; keeps prefetch in flight ----
    if (st <= 13)      asm volatile("s_waitcnt vmcnt(8)" ::: "memory");
    else if (st <= 15) asm volatile("s_waitcnt vmcnt(4)" ::: "memory");
    else               asm volatile("s_waitcnt vmcnt(0)" ::: "memory");
    // ---- tr-reads of buf[st%3] + MFMA ----
    const unsigned trb = trb_ + (unsigned)((st % 3) * 4096);
    i32x2 t00, t01, t10, t11, t20, t21, t30, t31;
    asm volatile("ds_read_b64_tr_b16 %0, %1 offset:0"    : "=v"(t00) : "v"(trb) : "memory");
    asm volatile("ds_read_b64_tr_b16 %0, %1 offset:512"  : "=v"(t01) : "v"(trb) : "memory");
    asm volatile("ds_read_b64_tr_b16 %0, %1 offset:1024" : "=v"(t10) : "v"(trb) : "memory");
    asm volatile("ds_read_b64_tr_b16 %0, %1 offset:1536" : "=v"(t11) : "v"(trb) : "memory");
    asm volatile("ds_read_b64_tr_b16 %0, %1 offset:2048" : "=v"(t20) : "v"(trb) : "memory");
    asm volatile("ds_read_b64_tr_b16 %0, %1 offset:2560" : "=v"(t21) : "v"(trb) : "memory");
    asm volatile("ds_read_b64_tr_b16 %0, %1 offset:3072" : "=v"(t30) : "v"(trb) : "memory");
    asm volatile("ds_read_b64_tr_b16 %0, %1 offset:3584" : "=v"(t31) : "v"(trb) : "memory");
    asm volatile("s_waitcnt lgkmcnt(0)" ::: "memory");
    __builtin_amdgcn_sched_barrier(0);
    const bf16x8 bfr0 = pack_bfr(t00, t01);
    const bf16x8 bfr1 = pack_bfr(t10, t11);
    const bf16x8 bfr2 = pack_bfr(t20, t21);
    const bf16x8 bfr3 = pack_bfr(t30, t31);
    acc[0][0] = __builtin_amdgcn_mfma_f32_16x16x32_bf16(af0, bfr0, acc[0][0], 0, 0, 0);
    acc[0][1] = __builtin_amdgcn_mfma_f32_16x16x32_bf16(af0, bfr1, acc[0][1], 0, 0, 0);
    acc[0][2] = __builtin_amdgcn_mfma_f32_16x16x32_bf16(af0, bfr2, acc[0][2], 0, 0, 0);
    acc[0][3] = __builtin_amdgcn_mfma_f32_16x16x32_bf16(af0, bfr3, acc[0][3], 0, 0, 0);
    acc[1][0] = __builtin_amdgcn_mfma_f32_16x16x32_bf16(af1, bfr0, acc[1][0], 0, 0, 0);
    acc[1][1] = __builtin_amdgcn_mfma_f32_16x16x32_bf16(af1, bfr1, acc[1][1], 0, 0, 0);
    acc[1][2] = __builtin_amdgcn_mfma_f32_16x16x32_bf16(af1, bfr2, acc[1][2], 0, 0, 0);
    acc[1][3] = __builtin_amdgcn_mfma_f32_16x16x32_bf16(af1, bfr3, acc[1][3], 0, 0, 0);
    acc[2][0] = __builtin_amdgcn_mfma_f32_16x16x32_bf16(af2, bfr0, acc[2][0], 0, 0, 0);
    acc[2][1] = __builtin_amdgcn_mfma_f32_16x16x32_bf16(af2, bfr1, acc[2][1], 0, 0, 0);
    acc[2][2] = __builtin_amdgcn_mfma_f32_16x16x32_bf16(af2, bfr2, acc[2][2], 0, 0, 0);
    acc[2][3] = __builtin_amdgcn_mfma_f32_16x16x32_bf16(af2, bfr3, acc[2][3], 0, 0, 0);
    acc[3][0] = __builtin_amdgcn_mfma_f32_16x16x32_bf16(af3, bfr0, acc[3][0], 0, 0, 0);
    acc[3][1] = __builtin_amdgcn_mfma_f32_16x16x32_bf16(af3, bfr1, acc[3][1], 0, 0, 0);
    acc[3][2] = __builtin_amdgcn_mfma_f32_16x16x32_bf16(af3, bfr2, acc[3][2], 0, 0, 0);
    acc[3][3] = __builtin_amdgcn_mfma_f32_16x16x32_bf16(af3, bfr3, acc[3][3], 0, 0, 0);
  }

  // ---- epilogue: direct in-register transpose stores (all static) ----
  // C/D: col(b16i)=batch b, row in m-tile = hi*4+j, pixel = p0+4wv+px.
  // 4 waves of the block fill each 64B output line -> merges in L2.
#pragma unroll
  for (int m = 0; m < 4; ++m)
#pragma unroll
    for (int j = 0; j < 4; ++j) {
      const float4 v = make_float4(acc[m][0][j], acc[m][1][j],
                                   acc[m][2][j], acc[m][3][j]);
      *(float4*)(out +
                 ((size_t)(b16i * 64 + m * 16 + hi * 4 + j)) * NHW +
                 p0 + 4 * wv) = v;
    }
}

// ---------------------------------------------------------------------------
// Fallback (workspace too small): direct gather, slow but correct.
// ---------------------------------------------------------------------------
__global__ __launch_bounds__(256) void hashconv_naive_kernel(
    const int* __restrict__ ht, const float* __restrict__ x,
    const float* __restrict__ w, float* __restrict__ out) {
  const int wave = (blockIdx.x * 256 + threadIdx.x) >> 6;
  const int lane = threadIdx.x & 63;
  const int b = wave >> 14;
  const int p = wave & (NHW - 1);
  float acc = 0.f;
  for (int q = 0; q < KC; ++q) {
    const int idx = __builtin_amdgcn_readlane(ht[(size_t)p * KC + q], 0);
    const float xv = x[(size_t)b * CHW + idx];
    acc = fmaf(w[(size_t)lane * KC + q], xv, acc);
  }
  out[((size_t)(b * 64 + lane)) * NHW + p] = acc;
}

extern "C" void kernel_launch(void* const* d_in, const int* in_sizes, int n_in,
                              void* d_out, int out_size, void* d_ws, size_t ws_size,
                              hipStream_t stream) {
  const float* x  = (const float*)d_in[0];
  const int*   ht = (const int*)d_in[1];
  const float* w  = (const float*)d_in[2];
  float* out = (float*)d_out;

  const size_t xT_elems = (size_t)CHW * NB;      // bf16
  const size_t wP_elems = (size_t)18 * 4 * 64 * 8;
  const size_t need = (xT_elems + wP_elems) * sizeof(unsigned short);

  if (ws_size >= need) {
    unsigned short* xT = (unsigned short*)d_ws;
    unsigned short* wP = xT + xT_elems;
    transpose_x_bf16<<<CHW / 256, 256, 0, stream>>>(x, xT);
    prep_w<<<(int)(wP_elems / 256), 256, 0, stream>>>(w, wP);
    hashconv_mfma<<<NHW / 16, 256, 0, stream>>>(ht, xT, wP, out);
  } else {
    hashconv_naive_kernel<<<(NB * NHW * 64) / 256, 256, 0, stream>>>(ht, x, w, out);
  }
}